// Round 12
// baseline (1543.271 us; speedup 1.0000x reference)
//
#include <hip/hip_runtime.h>
#include <float.h>

#define NS 1536
#define DD 64

// ws layout (float elements)
static const size_t OFF_A  = 0;                          // A = h_sat + b1: [1536][64]
static const size_t OFF_C2 = 98304;                      // C2 = h_uav transposed [16][1536][4]
static const size_t OFF_L  = 196608;                     // logits [1536][1536]
static const size_t OFF_AS = 196608 + (size_t)NS * NS;   // int assign [1536]

// ---------------- Kernel A: first-layer projections ----------------
__global__ __launch_bounds__(64) void kA(const float* __restrict__ sat,
                                         const float* __restrict__ uav,
                                         const float* __restrict__ W1,
                                         const float* __restrict__ b1,
                                         float* __restrict__ A,
                                         float* __restrict__ C2) {
    const int row = blockIdx.x;
    const int d = threadIdx.x;
    float accA = b1[d];
    float accC = 0.f;
    const float* __restrict__ satr = sat + row * DD;
    const float* __restrict__ uavr = uav + row * DD;
#pragma unroll 8
    for (int k = 0; k < DD; ++k) {
        accA = fmaf(satr[k], W1[k * DD + d], accA);
        accC = fmaf(uavr[k], W1[(DD + k) * DD + d], accC);
    }
    A[row * DD + d] = accA;
    C2[((size_t)(d >> 2) * NS + row) * 4 + (d & 3)] = accC;
}

// ---------------- Kernel B: all-pairs logits ----------------
__global__ __launch_bounds__(256) void kB(const float* __restrict__ A,
                                          const float* __restrict__ C2,
                                          const float* __restrict__ W2,
                                          const float* __restrict__ b2,
                                          const float* __restrict__ W3,
                                          float* __restrict__ L) {
    const int lane = threadIdx.x & 63;
    const int wave = threadIdx.x >> 6;
    const int i = __builtin_amdgcn_readfirstlane(blockIdx.x * 4 + wave);
    const int jbase = blockIdx.y * 256;
    const float* __restrict__ Ar = A + (size_t)i * DD;

    float u[4][32];
#pragma unroll
    for (int o = 0; o < 32; ++o) {
        const float b = b2[o];
        u[0][o] = b; u[1][o] = b; u[2][o] = b; u[3][o] = b;
    }

    const float4* __restrict__ C2v = (const float4*)C2;

    for (int d4 = 0; d4 < 16; ++d4) {
        float c[4][4];
#pragma unroll
        for (int p = 0; p < 4; ++p) {
            const float4 t = C2v[(size_t)d4 * NS + jbase + p * 64 + lane];
            c[p][0] = t.x; c[p][1] = t.y; c[p][2] = t.z; c[p][3] = t.w;
        }
#pragma unroll
        for (int dd = 0; dd < 4; ++dd) {
            const float a = Ar[d4 * 4 + dd];
            const float v0 = fmaxf(a + c[0][dd], 0.f);
            const float v1 = fmaxf(a + c[1][dd], 0.f);
            const float v2 = fmaxf(a + c[2][dd], 0.f);
            const float v3 = fmaxf(a + c[3][dd], 0.f);
            const float* __restrict__ w2r = W2 + (d4 * 4 + dd) * 32;
#pragma unroll
            for (int o = 0; o < 32; ++o) {
                const float w = w2r[o];
                u[0][o] = fmaf(v0, w, u[0][o]);
                u[1][o] = fmaf(v1, w, u[1][o]);
                u[2][o] = fmaf(v2, w, u[2][o]);
                u[3][o] = fmaf(v3, w, u[3][o]);
            }
        }
    }

#pragma unroll
    for (int p = 0; p < 4; ++p) {
        float acc = 0.f;
#pragma unroll
        for (int o = 0; o < 32; ++o)
            acc = fmaf(fmaxf(u[p][o], 0.f), W3[o], acc);
        L[(size_t)i * NS + jbase + p * 64 + lane] = acc;
    }
}

// Wave-wide max of a u32 via DPP (pure VALU). bound_ctrl=true fills invalid
// source lanes with 0 -> 0 must be a safe identity (all keys used are > 0).
// Lane 63 holds the wave max afterwards.
__device__ __forceinline__ unsigned wave_max_u32_dpp(unsigned x) {
    unsigned t;
    t = (unsigned)__builtin_amdgcn_update_dpp(0, (int)x, 0x111, 0xF, 0xF, true); // row_shr:1
    x = x > t ? x : t;
    t = (unsigned)__builtin_amdgcn_update_dpp(0, (int)x, 0x112, 0xF, 0xF, true); // row_shr:2
    x = x > t ? x : t;
    t = (unsigned)__builtin_amdgcn_update_dpp(0, (int)x, 0x114, 0xF, 0xF, true); // row_shr:4
    x = x > t ? x : t;
    t = (unsigned)__builtin_amdgcn_update_dpp(0, (int)x, 0x118, 0xF, 0xF, true); // row_shr:8
    x = x > t ? x : t;
    t = (unsigned)__builtin_amdgcn_update_dpp(0, (int)x, 0x142, 0xF, 0xF, true); // row_bcast:15
    x = x > t ? x : t;
    t = (unsigned)__builtin_amdgcn_update_dpp(0, (int)x, 0x143, 0xF, 0xF, true); // row_bcast:31
    x = x > t ? x : t;
    return x;
}

// async global->LDS DMA, 16B per lane: LDS dest = wave-uniform base + lane*16,
// global src is per-lane. Counted by vmcnt (m03/m97/m104).
__device__ __forceinline__ void gload_lds16(const float* gsrc, float* ldst) {
    __builtin_amdgcn_global_load_lds(
        (const __attribute__((address_space(1))) void*)gsrc,
        (__attribute__((address_space(3))) void*)ldst, 16, 0, 0);
}

// ---------------- Kernel D: dense greedy, DMA-fed LDS ring ------------------
// Round-11 post-mortem: the rv[4][6] register ring (96 VGPR) was destroyed by
// the register allocator (VGPR_Count=84) -> loads sunk to use -> ~800cy load
// latency on every row's serial chain. Fix: values go global->LDS via
// global_load_lds DMA (no VGPR dest, no producer wave, no sync protocol);
// prefetch depth 4 rows enforced by EXPLICIT counted s_waitcnt vmcnt(18)
// (oldest-first retirement => row i's 6 loads landed). Per row:
//   vmcnt(18) [satisfied in steady state] -> 6x ds_read_b128 (~120cy)
//   -> r11's pure-VALU body (mask cndmask / fmax tree / min-col / 2-phase DPP)
//   -> commit (owner-lane 'dead' bit, LDS assign store)
//   -> issue 6 DMA loads for row i+4 into slot (i+4)&7 (off-chain).
// Tail issues clamped to row NS-1 so the vmcnt constant stays valid (r11 trick).
__global__ __launch_bounds__(64) void kD(const float* __restrict__ L,
                                         int* __restrict__ assign) {
    __shared__ float ring[8][NS];      // 48KB row ring
    __shared__ int assign_s[NS];
    const int lane = threadIdx.x;

    // prologue: DMA rows 0..3 into slots 0..3 (issue order = retire order)
    for (int r = 0; r < 4; ++r) {
#pragma unroll
        for (int m = 0; m < 6; ++m)
            gload_lds16(L + (size_t)r * NS + m * 256 + 4 * lane,
                        &ring[r][m * 256]);
    }

    unsigned dead = 0u;   // bit (4m+sub) set <=> col 4*lane+256m+sub used

    for (int i = 0; i < NS; ++i) {
        // row i's 6 loads are the oldest; <=18 outstanding => they landed
        asm volatile("s_waitcnt vmcnt(18)" ::: "memory");

        const float4* __restrict__ S4 = (const float4*)&ring[i & 7][0];
        const float4 v0 = S4[lane];
        const float4 v1 = S4[lane + 64];
        const float4 v2 = S4[lane + 128];
        const float4 v3 = S4[lane + 192];
        const float4 v4 = S4[lane + 256];
        const float4 v5 = S4[lane + 320];

        // ---- mask apply (dead from previous rows) ----
        float x[24];
        x[0]  = (dead & (1u << 0))  ? -FLT_MAX : v0.x;
        x[1]  = (dead & (1u << 1))  ? -FLT_MAX : v0.y;
        x[2]  = (dead & (1u << 2))  ? -FLT_MAX : v0.z;
        x[3]  = (dead & (1u << 3))  ? -FLT_MAX : v0.w;
        x[4]  = (dead & (1u << 4))  ? -FLT_MAX : v1.x;
        x[5]  = (dead & (1u << 5))  ? -FLT_MAX : v1.y;
        x[6]  = (dead & (1u << 6))  ? -FLT_MAX : v1.z;
        x[7]  = (dead & (1u << 7))  ? -FLT_MAX : v1.w;
        x[8]  = (dead & (1u << 8))  ? -FLT_MAX : v2.x;
        x[9]  = (dead & (1u << 9))  ? -FLT_MAX : v2.y;
        x[10] = (dead & (1u << 10)) ? -FLT_MAX : v2.z;
        x[11] = (dead & (1u << 11)) ? -FLT_MAX : v2.w;
        x[12] = (dead & (1u << 12)) ? -FLT_MAX : v3.x;
        x[13] = (dead & (1u << 13)) ? -FLT_MAX : v3.y;
        x[14] = (dead & (1u << 14)) ? -FLT_MAX : v3.z;
        x[15] = (dead & (1u << 15)) ? -FLT_MAX : v3.w;
        x[16] = (dead & (1u << 16)) ? -FLT_MAX : v4.x;
        x[17] = (dead & (1u << 17)) ? -FLT_MAX : v4.y;
        x[18] = (dead & (1u << 18)) ? -FLT_MAX : v4.z;
        x[19] = (dead & (1u << 19)) ? -FLT_MAX : v4.w;
        x[20] = (dead & (1u << 20)) ? -FLT_MAX : v5.x;
        x[21] = (dead & (1u << 21)) ? -FLT_MAX : v5.y;
        x[22] = (dead & (1u << 22)) ? -FLT_MAX : v5.z;
        x[23] = (dead & (1u << 23)) ? -FLT_MAX : v5.w;

        // ---- per-lane max (tree; max3-fusible) ----
        float p[6];
#pragma unroll
        for (int m = 0; m < 6; ++m)
            p[m] = fmaxf(fmaxf(x[4 * m], x[4 * m + 1]),
                         fmaxf(x[4 * m + 2], x[4 * m + 3]));
        const float bv = fmaxf(fmaxf(fmaxf(p[0], p[1]), fmaxf(p[2], p[3])),
                               fmaxf(p[4], p[5]));

        // ---- per-lane min col among x==bv ----
        int mm[6];
#pragma unroll
        for (int m = 0; m < 6; ++m) {
            const int c0 = 4 * lane + 256 * m;
            const int m0 = (x[4 * m + 0] == bv) ? (c0 + 0) : 4095;
            const int m1 = (x[4 * m + 1] == bv) ? (c0 + 1) : 4095;
            const int m2 = (x[4 * m + 2] == bv) ? (c0 + 2) : 4095;
            const int m3 = (x[4 * m + 3] == bv) ? (c0 + 3) : 4095;
            mm[m] = min(min(m0, m1), min(m2, m3));
        }
        const int ci = min(min(min(mm[0], mm[1]), min(mm[2], mm[3])),
                           min(mm[4], mm[5]));

        // ---- cross-lane argmax: 2-phase DPP (val desc, col asc) ----
        unsigned b = __float_as_uint(bv);
        unsigned key = (b & 0x80000000u) ? ~b : (b | 0x80000000u);
        const unsigned wk = wave_max_u32_dpp(key);
        const unsigned maxk = (unsigned)__builtin_amdgcn_readlane((int)wk, 63);
        unsigned cand = (key == maxk) ? (unsigned)(4096 - ci) : 0u;
        const unsigned wc = wave_max_u32_dpp(cand);
        const unsigned mc = (unsigned)__builtin_amdgcn_readlane((int)wc, 63);
        const int j = 4096 - (int)mc;

        // ---- commit ----
        if (lane == 0) assign_s[i] = j;
        const unsigned jb = 1u << ((((unsigned)j >> 8) << 2) + ((unsigned)j & 3u));
        if ((((unsigned)j >> 2) & 63u) == (unsigned)lane) dead |= jb;

        // ---- issue DMA for row i+4 into slot (i+4)&7 (off-chain) ----
        {
            int r2 = i + 4; r2 = (r2 < NS) ? r2 : (NS - 1);
            float* dst = &ring[(i + 4) & 7][0];
#pragma unroll
            for (int m = 0; m < 6; ++m)
                gload_lds16(L + (size_t)r2 * NS + m * 256 + 4 * lane,
                            dst + m * 256);
        }
    }

    for (int k = lane; k < NS; k += 64) assign[k] = assign_s[k];
}

// ---------------- Kernel E: emit [1536][2][64] output ----------------
__global__ __launch_bounds__(128) void kE(const float* __restrict__ sat,
                                          const float* __restrict__ uav,
                                          const int* __restrict__ assign,
                                          float* __restrict__ out) {
    const int i = blockIdx.x;
    const int t = threadIdx.x;
    if (t < 64) out[(size_t)i * 128 + t] = sat[(size_t)i * DD + t];
    else        out[(size_t)i * 128 + t] = uav[(size_t)assign[i] * DD + (t - 64)];
}

extern "C" void kernel_launch(void* const* d_in, const int* in_sizes, int n_in,
                              void* d_out, int out_size, void* d_ws, size_t ws_size,
                              hipStream_t stream) {
    const float* sat = (const float*)d_in[0];
    const float* uav = (const float*)d_in[1];
    const float* W1  = (const float*)d_in[2];
    const float* b1  = (const float*)d_in[3];
    const float* W2  = (const float*)d_in[4];
    const float* b2  = (const float*)d_in[5];
    const float* W3  = (const float*)d_in[6];
    // d_in[7] = b3: sigmoid(x+b3) monotone in x — argmax unchanged.

    float* ws = (float*)d_ws;
    float* A   = ws + OFF_A;
    float* C2  = ws + OFF_C2;
    float* L   = ws + OFF_L;
    int* assign = (int*)(ws + OFF_AS);

    hipLaunchKernelGGL(kA, dim3(NS), dim3(64), 0, stream, sat, uav, W1, b1, A, C2);
    hipLaunchKernelGGL(kB, dim3(NS / 4, NS / 256), dim3(256), 0, stream,
                       A, C2, W2, b2, W3, L);
    hipLaunchKernelGGL(kD, dim3(1), dim3(64), 0, stream, L, assign);
    hipLaunchKernelGGL(kE, dim3(NS), dim3(128), 0, stream, sat, uav, assign,
                       (float*)d_out);
}

// Round 13
// 989.441 us; speedup vs baseline: 1.5597x; 1.5597x over previous
//
#include <hip/hip_runtime.h>
#include <float.h>

#define NS 1536
#define DD 64

typedef float f32x4 __attribute__((ext_vector_type(4)));

// ws layout (float elements)
static const size_t OFF_A  = 0;                          // A = h_sat + b1: [1536][64]
static const size_t OFF_C2 = 98304;                      // C2 = h_uav transposed [16][1536][4]
static const size_t OFF_L  = 196608;                     // logits [1536][1536]
static const size_t OFF_AS = 196608 + (size_t)NS * NS;   // int assign [1536]

// ---------------- Kernel A: first-layer projections ----------------
__global__ __launch_bounds__(64) void kA(const float* __restrict__ sat,
                                         const float* __restrict__ uav,
                                         const float* __restrict__ W1,
                                         const float* __restrict__ b1,
                                         float* __restrict__ A,
                                         float* __restrict__ C2) {
    const int row = blockIdx.x;
    const int d = threadIdx.x;
    float accA = b1[d];
    float accC = 0.f;
    const float* __restrict__ satr = sat + row * DD;
    const float* __restrict__ uavr = uav + row * DD;
#pragma unroll 8
    for (int k = 0; k < DD; ++k) {
        accA = fmaf(satr[k], W1[k * DD + d], accA);
        accC = fmaf(uavr[k], W1[(DD + k) * DD + d], accC);
    }
    A[row * DD + d] = accA;
    C2[((size_t)(d >> 2) * NS + row) * 4 + (d & 3)] = accC;
}

// ---------------- Kernel B: all-pairs logits ----------------
__global__ __launch_bounds__(256) void kB(const float* __restrict__ A,
                                          const float* __restrict__ C2,
                                          const float* __restrict__ W2,
                                          const float* __restrict__ b2,
                                          const float* __restrict__ W3,
                                          float* __restrict__ L) {
    const int lane = threadIdx.x & 63;
    const int wave = threadIdx.x >> 6;
    const int i = __builtin_amdgcn_readfirstlane(blockIdx.x * 4 + wave);
    const int jbase = blockIdx.y * 256;
    const float* __restrict__ Ar = A + (size_t)i * DD;

    float u[4][32];
#pragma unroll
    for (int o = 0; o < 32; ++o) {
        const float b = b2[o];
        u[0][o] = b; u[1][o] = b; u[2][o] = b; u[3][o] = b;
    }

    const float4* __restrict__ C2v = (const float4*)C2;

    for (int d4 = 0; d4 < 16; ++d4) {
        float c[4][4];
#pragma unroll
        for (int p = 0; p < 4; ++p) {
            const float4 t = C2v[(size_t)d4 * NS + jbase + p * 64 + lane];
            c[p][0] = t.x; c[p][1] = t.y; c[p][2] = t.z; c[p][3] = t.w;
        }
#pragma unroll
        for (int dd = 0; dd < 4; ++dd) {
            const float a = Ar[d4 * 4 + dd];
            const float v0 = fmaxf(a + c[0][dd], 0.f);
            const float v1 = fmaxf(a + c[1][dd], 0.f);
            const float v2 = fmaxf(a + c[2][dd], 0.f);
            const float v3 = fmaxf(a + c[3][dd], 0.f);
            const float* __restrict__ w2r = W2 + (d4 * 4 + dd) * 32;
#pragma unroll
            for (int o = 0; o < 32; ++o) {
                const float w = w2r[o];
                u[0][o] = fmaf(v0, w, u[0][o]);
                u[1][o] = fmaf(v1, w, u[1][o]);
                u[2][o] = fmaf(v2, w, u[2][o]);
                u[3][o] = fmaf(v3, w, u[3][o]);
            }
        }
    }

#pragma unroll
    for (int p = 0; p < 4; ++p) {
        float acc = 0.f;
#pragma unroll
        for (int o = 0; o < 32; ++o)
            acc = fmaf(fmaxf(u[p][o], 0.f), W3[o], acc);
        L[(size_t)i * NS + jbase + p * 64 + lane] = acc;
    }
}

// Wave-wide max of a u32 via DPP (pure VALU). bound_ctrl=true fills invalid
// source lanes with 0 -> 0 must be a safe identity (all keys used are > 0).
// Lane 63 holds the wave max afterwards.
__device__ __forceinline__ unsigned wave_max_u32_dpp(unsigned x) {
    unsigned t;
    t = (unsigned)__builtin_amdgcn_update_dpp(0, (int)x, 0x111, 0xF, 0xF, true); // row_shr:1
    x = x > t ? x : t;
    t = (unsigned)__builtin_amdgcn_update_dpp(0, (int)x, 0x112, 0xF, 0xF, true); // row_shr:2
    x = x > t ? x : t;
    t = (unsigned)__builtin_amdgcn_update_dpp(0, (int)x, 0x114, 0xF, 0xF, true); // row_shr:4
    x = x > t ? x : t;
    t = (unsigned)__builtin_amdgcn_update_dpp(0, (int)x, 0x118, 0xF, 0xF, true); // row_shr:8
    x = x > t ? x : t;
    t = (unsigned)__builtin_amdgcn_update_dpp(0, (int)x, 0x142, 0xF, 0xF, true); // row_bcast:15
    x = x > t ? x : t;
    t = (unsigned)__builtin_amdgcn_update_dpp(0, (int)x, 0x143, 0xF, 0xF, true); // row_bcast:31
    x = x > t ? x : t;
    return x;
}

// Issue 6x global_load_dwordx4 for one row (96B/lane, coalesced) via PINNED
// inline asm: volatile -> compiler cannot sink/reschedule the issue point;
// the waitcnt pass cannot see a load inside asm -> no auto vmcnt(0) drain
// (the r12 failure). Dest registers are redefined here: all readers of the
// previous value are WAR-ordered before this point by the scheduler.
#define ISSUE6(arr, rowptr) do {                                              \
    unsigned long long _a0 = (unsigned long long)(rowptr);                    \
    unsigned long long _a1 = (unsigned long long)((rowptr) + 768);            \
    asm volatile("global_load_dwordx4 %0, %1, off"             : "=&v"(arr[0]) : "v"(_a0)); \
    asm volatile("global_load_dwordx4 %0, %1, off offset:1024" : "=&v"(arr[1]) : "v"(_a0)); \
    asm volatile("global_load_dwordx4 %0, %1, off offset:2048" : "=&v"(arr[2]) : "v"(_a0)); \
    asm volatile("global_load_dwordx4 %0, %1, off"             : "=&v"(arr[3]) : "v"(_a1)); \
    asm volatile("global_load_dwordx4 %0, %1, off offset:1024" : "=&v"(arr[4]) : "v"(_a1)); \
    asm volatile("global_load_dwordx4 %0, %1, off offset:2048" : "=&v"(arr[5]) : "v"(_a1)); \
} while (0)

// One greedy row: counted wait for THIS row's 6 loads (oldest of 24), pure-VALU
// masked argmax (r11 body, refcheck'd), commit, then issue row i+4 into the
// same register slot (reuse distance 4 rows ~2000cy >> HBM latency).
__device__ __forceinline__ void row_body(f32x4 (&arr)[6], int i, unsigned& dead,
                                         int lane, int* assign_s,
                                         const float* Lb) {
    asm volatile("s_waitcnt vmcnt(18)" ::: "memory");
    __builtin_amdgcn_sched_barrier(0);   // rule #18: pin consumers below wait

    float x[24];
#pragma unroll
    for (int m = 0; m < 6; ++m) {
#pragma unroll
        for (int s = 0; s < 4; ++s)
            x[4 * m + s] = (dead & (1u << (4 * m + s))) ? -FLT_MAX : arr[m][s];
    }

    // per-lane max (tree; max3-fusible)
    float p[6];
#pragma unroll
    for (int m = 0; m < 6; ++m)
        p[m] = fmaxf(fmaxf(x[4 * m], x[4 * m + 1]),
                     fmaxf(x[4 * m + 2], x[4 * m + 3]));
    const float bv = fmaxf(fmaxf(fmaxf(p[0], p[1]), fmaxf(p[2], p[3])),
                           fmaxf(p[4], p[5]));

    // per-lane min col among x==bv
    int mm[6];
#pragma unroll
    for (int m = 0; m < 6; ++m) {
        const int c0 = 4 * lane + 256 * m;
        const int m0 = (x[4 * m + 0] == bv) ? (c0 + 0) : 4095;
        const int m1 = (x[4 * m + 1] == bv) ? (c0 + 1) : 4095;
        const int m2 = (x[4 * m + 2] == bv) ? (c0 + 2) : 4095;
        const int m3 = (x[4 * m + 3] == bv) ? (c0 + 3) : 4095;
        mm[m] = min(min(m0, m1), min(m2, m3));
    }
    const int ci = min(min(min(mm[0], mm[1]), min(mm[2], mm[3])),
                       min(mm[4], mm[5]));

    // cross-lane argmax: 2-phase DPP (val desc, col asc)
    unsigned b = __float_as_uint(bv);
    unsigned key = (b & 0x80000000u) ? ~b : (b | 0x80000000u);
    const unsigned wk = wave_max_u32_dpp(key);
    const unsigned maxk = (unsigned)__builtin_amdgcn_readlane((int)wk, 63);
    unsigned cand = (key == maxk) ? (unsigned)(4096 - ci) : 0u;
    const unsigned wc = wave_max_u32_dpp(cand);
    const unsigned mc = (unsigned)__builtin_amdgcn_readlane((int)wc, 63);
    const int j = 4096 - (int)mc;

    // commit (LDS store off-chain; owner-lane dead-bit update)
    if (lane == 0) assign_s[i] = j;
    const unsigned jb = 1u << ((((unsigned)j >> 8) << 2) + ((unsigned)j & 3u));
    if ((((unsigned)j >> 2) & 63u) == (unsigned)lane) dead |= jb;

    // refill this slot with row i+4 (clamped tail keeps vmcnt arithmetic)
    int r2 = i + 4; r2 = (r2 < NS) ? r2 : (NS - 1);
    ISSUE6(arr, Lb + (size_t)r2 * NS);
}

// ---------------- Kernel D: dense greedy, register ring via pinned asm ------
// r11 proved the pure-VALU body but plain-HIP ring loads were sunk by regalloc
// (VGPR=84 < ring size). r12's LDS-DMA ring hit the compiler's conservative
// vmcnt(0) drain before every ds_read (~1600cy/row exposed). This version
// keeps values in 96 ring VGPRs defined by asm-volatile loads the compiler
// can neither sink nor auto-drain; the ONLY wait is the counted vmcnt(18).
__global__ __launch_bounds__(64) void kD(const float* __restrict__ L,
                                         int* __restrict__ assign) {
    __shared__ int assign_s[NS];
    const int lane = threadIdx.x;
    const float* Lb = L + 4 * lane;   // per-lane base (16B/lane pattern)

    f32x4 r0[6], r1[6], r2[6], r3[6];
    ISSUE6(r0, Lb + (size_t)0 * NS);
    ISSUE6(r1, Lb + (size_t)1 * NS);
    ISSUE6(r2, Lb + (size_t)2 * NS);
    ISSUE6(r3, Lb + (size_t)3 * NS);

    unsigned dead = 0u;   // bit (4m+sub) set <=> col 4*lane+256m+sub used

    for (int i = 0; i < NS; i += 4) {
        row_body(r0, i + 0, dead, lane, assign_s, Lb);
        row_body(r1, i + 1, dead, lane, assign_s, Lb);
        row_body(r2, i + 2, dead, lane, assign_s, Lb);
        row_body(r3, i + 3, dead, lane, assign_s, Lb);
    }

    for (int k = lane; k < NS; k += 64) assign[k] = assign_s[k];
}

// ---------------- Kernel E: emit [1536][2][64] output ----------------
__global__ __launch_bounds__(128) void kE(const float* __restrict__ sat,
                                          const float* __restrict__ uav,
                                          const int* __restrict__ assign,
                                          float* __restrict__ out) {
    const int i = blockIdx.x;
    const int t = threadIdx.x;
    if (t < 64) out[(size_t)i * 128 + t] = sat[(size_t)i * DD + t];
    else        out[(size_t)i * 128 + t] = uav[(size_t)assign[i] * DD + (t - 64)];
}

extern "C" void kernel_launch(void* const* d_in, const int* in_sizes, int n_in,
                              void* d_out, int out_size, void* d_ws, size_t ws_size,
                              hipStream_t stream) {
    const float* sat = (const float*)d_in[0];
    const float* uav = (const float*)d_in[1];
    const float* W1  = (const float*)d_in[2];
    const float* b1  = (const float*)d_in[3];
    const float* W2  = (const float*)d_in[4];
    const float* b2  = (const float*)d_in[5];
    const float* W3  = (const float*)d_in[6];
    // d_in[7] = b3: sigmoid(x+b3) monotone in x — argmax unchanged.

    float* ws = (float*)d_ws;
    float* A   = ws + OFF_A;
    float* C2  = ws + OFF_C2;
    float* L   = ws + OFF_L;
    int* assign = (int*)(ws + OFF_AS);

    hipLaunchKernelGGL(kA, dim3(NS), dim3(64), 0, stream, sat, uav, W1, b1, A, C2);
    hipLaunchKernelGGL(kB, dim3(NS / 4, NS / 256), dim3(256), 0, stream,
                       A, C2, W2, b2, W3, L);
    hipLaunchKernelGGL(kD, dim3(1), dim3(64), 0, stream, L, assign);
    hipLaunchKernelGGL(kE, dim3(NS), dim3(128), 0, stream, sat, uav, assign,
                       (float*)d_out);
}

// Round 15
// 808.344 us; speedup vs baseline: 1.9092x; 1.2240x over previous
//
#include <hip/hip_runtime.h>
#include <float.h>

#define NS 1536
#define DD 64

// ws layout (float elements)
static const size_t OFF_A  = 0;                          // A = h_sat + b1: [1536][64]
static const size_t OFF_C2 = 98304;                      // C2 = h_uav transposed [16][1536][4]
static const size_t OFF_L  = 196608;                     // logits [1536][1536]
static const size_t OFF_AS = 196608 + (size_t)NS * NS;   // int assign [1536]
// top_idx (ushort, 1536*256 = 786432 B) ALIASES the A/C2 region (dead after kB).

// ---------------- Kernel A: first-layer projections ----------------
__global__ __launch_bounds__(64) void kA(const float* __restrict__ sat,
                                         const float* __restrict__ uav,
                                         const float* __restrict__ W1,
                                         const float* __restrict__ b1,
                                         float* __restrict__ A,
                                         float* __restrict__ C2) {
    const int row = blockIdx.x;
    const int d = threadIdx.x;
    float accA = b1[d];
    float accC = 0.f;
    const float* __restrict__ satr = sat + row * DD;
    const float* __restrict__ uavr = uav + row * DD;
#pragma unroll 8
    for (int k = 0; k < DD; ++k) {
        accA = fmaf(satr[k], W1[k * DD + d], accA);
        accC = fmaf(uavr[k], W1[(DD + k) * DD + d], accC);
    }
    A[row * DD + d] = accA;
    C2[((size_t)(d >> 2) * NS + row) * 4 + (d & 3)] = accC;
}

// ---------------- Kernel B: all-pairs logits ----------------
__global__ __launch_bounds__(256) void kB(const float* __restrict__ A,
                                          const float* __restrict__ C2,
                                          const float* __restrict__ W2,
                                          const float* __restrict__ b2,
                                          const float* __restrict__ W3,
                                          float* __restrict__ L) {
    const int lane = threadIdx.x & 63;
    const int wave = threadIdx.x >> 6;
    const int i = __builtin_amdgcn_readfirstlane(blockIdx.x * 4 + wave);
    const int jbase = blockIdx.y * 256;
    const float* __restrict__ Ar = A + (size_t)i * DD;

    float u[4][32];
#pragma unroll
    for (int o = 0; o < 32; ++o) {
        const float b = b2[o];
        u[0][o] = b; u[1][o] = b; u[2][o] = b; u[3][o] = b;
    }

    const float4* __restrict__ C2v = (const float4*)C2;

    for (int d4 = 0; d4 < 16; ++d4) {
        float c[4][4];
#pragma unroll
        for (int p = 0; p < 4; ++p) {
            const float4 t = C2v[(size_t)d4 * NS + jbase + p * 64 + lane];
            c[p][0] = t.x; c[p][1] = t.y; c[p][2] = t.z; c[p][3] = t.w;
        }
#pragma unroll
        for (int dd = 0; dd < 4; ++dd) {
            const float a = Ar[d4 * 4 + dd];
            const float v0 = fmaxf(a + c[0][dd], 0.f);
            const float v1 = fmaxf(a + c[1][dd], 0.f);
            const float v2 = fmaxf(a + c[2][dd], 0.f);
            const float v3 = fmaxf(a + c[3][dd], 0.f);
            const float* __restrict__ w2r = W2 + (d4 * 4 + dd) * 32;
#pragma unroll
            for (int o = 0; o < 32; ++o) {
                const float w = w2r[o];
                u[0][o] = fmaf(v0, w, u[0][o]);
                u[1][o] = fmaf(v1, w, u[1][o]);
                u[2][o] = fmaf(v2, w, u[2][o]);
                u[3][o] = fmaf(v3, w, u[3][o]);
            }
        }
    }

#pragma unroll
    for (int p = 0; p < 4; ++p) {
        float acc = 0.f;
#pragma unroll
        for (int o = 0; o < 32; ++o)
            acc = fmaf(fmaxf(u[p][o], 0.f), W3[o], acc);
        L[(size_t)i * NS + jbase + p * 64 + lane] = acc;
    }
}

// ---------------- Kernel C: per-row sorted top-256 via 16-bit radix ----------------
// Swizzled layout: rank r lives at top[row*256 + (r&63)*4 + (r>>6)] so kD's
// uint2-per-lane read gives lane l ranks {l, l+64, l+128, l+192}.
__global__ __launch_bounds__(256) void kC(const float* __restrict__ L,
                                          unsigned short* __restrict__ top) {
    __shared__ int hist[256];
    __shared__ int suff[256];
    __shared__ float cv[1024];
    __shared__ int ci[1024];
    __shared__ int s_cnt, s_B0, s_base, s_B1;
    const int t = threadIdx.x;
    const int row = blockIdx.x;
    const float* __restrict__ Lr = L + (size_t)row * NS;

    top[row * 256 + t] = 0xFFFFu;   // sentinel (degenerate rows -> kD fallback)

    hist[t] = 0;
    if (t == 0) s_cnt = 0;
    __syncthreads();

    unsigned ub[6]; float fv[6];
#pragma unroll
    for (int k = 0; k < 6; ++k) {
        const float x = Lr[t + 256 * k];
        fv[k] = x;
        unsigned b = __float_as_uint(x);
        b = (b & 0x80000000u) ? ~b : (b | 0x80000000u);
        ub[k] = b;
        atomicAdd(&hist[b >> 24], 1);
    }
    __syncthreads();

    suff[t] = hist[t];
    __syncthreads();
    for (int off = 1; off < 256; off <<= 1) {
        const int v = (t + off < 256) ? suff[t + off] : 0;
        __syncthreads();
        suff[t] += v;
        __syncthreads();
    }
    if (suff[t] >= 256 && (t == 255 || suff[t + 1] < 256)) {
        s_B0 = t;
        s_base = (t == 255) ? 0 : suff[t + 1];
    }
    __syncthreads();
    const unsigned B0 = (unsigned)s_B0;
    const int base = s_base;

    hist[t] = 0;
    __syncthreads();
#pragma unroll
    for (int k = 0; k < 6; ++k)
        if ((ub[k] >> 24) == B0) atomicAdd(&hist[(ub[k] >> 16) & 255], 1);
    __syncthreads();
    suff[t] = hist[t];
    __syncthreads();
    for (int off = 1; off < 256; off <<= 1) {
        const int v = (t + off < 256) ? suff[t + off] : 0;
        __syncthreads();
        suff[t] += v;
        __syncthreads();
    }
    const int need = 256 - base;
    if (suff[t] >= need && (t == 255 || suff[t + 1] < need)) s_B1 = t;
    __syncthreads();
    const unsigned B1 = (unsigned)s_B1;
    const int m = base + suff[B1];
    if (m > 1024) return;

#pragma unroll
    for (int k = 0; k < 6; ++k) {
        const unsigned hi = ub[k] >> 24;
        const unsigned mid = (ub[k] >> 16) & 255u;
        if (hi > B0 || (hi == B0 && mid >= B1)) {
            const int pos = atomicAdd(&s_cnt, 1);
            cv[pos] = fv[k];
            ci[pos] = t + 256 * k;
        }
    }
    __syncthreads();

    for (int e = t; e < m; e += 256) {
        const float v = cv[e]; const int id = ci[e];
        int r = 0;
        for (int s2 = 0; s2 < m; ++s2) {
            const float vs = cv[s2];
            if (vs > v || (vs == v && ci[s2] < id)) ++r;
        }
        if (r < 256) top[row * 256 + (r & 63) * 4 + (r >> 6)] = (unsigned short)id;
    }
}

// Wave-wide max of a u32 via DPP (pure VALU, ~4-8cy/stage vs ~60cy/bpermute).
// bound_ctrl=true fills invalid source lanes with 0 -> 0 must be a safe
// identity (all our keys are > 0). Lane 63 holds the wave max afterwards.
__device__ __forceinline__ unsigned wave_max_u32_dpp(unsigned x) {
    unsigned t;
    t = (unsigned)__builtin_amdgcn_update_dpp(0, (int)x, 0x111, 0xF, 0xF, true); // row_shr:1
    x = x > t ? x : t;
    t = (unsigned)__builtin_amdgcn_update_dpp(0, (int)x, 0x112, 0xF, 0xF, true); // row_shr:2
    x = x > t ? x : t;
    t = (unsigned)__builtin_amdgcn_update_dpp(0, (int)x, 0x114, 0xF, 0xF, true); // row_shr:4
    x = x > t ? x : t;
    t = (unsigned)__builtin_amdgcn_update_dpp(0, (int)x, 0x118, 0xF, 0xF, true); // row_shr:8
    x = x > t ? x : t;
    t = (unsigned)__builtin_amdgcn_update_dpp(0, (int)x, 0x142, 0xF, 0xF, true); // row_bcast:15
    x = x > t ? x : t;
    t = (unsigned)__builtin_amdgcn_update_dpp(0, (int)x, 0x143, 0xF, 0xF, true); // row_bcast:31
    x = x > t ? x : t;
    return x;
}

// Exact masked argmax over the compact unused list. Chunk 0 indices come from
// the U8 register cache (refreshed each rebuild) -> no idx-LDS read on the
// serial chain; chunks >=512 (early rows only) fall back to U_s in LDS.
__device__ __forceinline__ int fb_argmax(const float* __restrict__ L, int i,
                                         int mU, const int (&U8)[8],
                                         const int* used_s,
                                         const unsigned short* U_s, int lane) {
    const float* __restrict__ Lr = L + (size_t)i * NS;
    float bv = -FLT_MAX; int bi = NS;
    {
        int idx[8]; int flc[8]; float vv[8];
#pragma unroll
        for (int c = 0; c < 8; ++c) {
            const int k = lane + (c << 6);
            idx[c] = (k < mU) ? U8[c] : 0;
        }
#pragma unroll
        for (int c = 0; c < 8; ++c) vv[c] = Lr[idx[c]];     // addr from regs
#pragma unroll
        for (int c = 0; c < 8; ++c) flc[c] = used_s[idx[c]];
#pragma unroll
        for (int c = 0; c < 8; ++c) {
            const int k = lane + (c << 6);
            if (k < mU && flc[c] == 0 &&
                (vv[c] > bv || (vv[c] == bv && idx[c] < bi))) {
                bv = vv[c]; bi = idx[c];
            }
        }
    }
    for (int kbase = 512; kbase < mU; kbase += 512) {
        int idx[8]; int flc[8]; float vv[8];
#pragma unroll
        for (int c = 0; c < 8; ++c) {
            const int k = kbase + lane + (c << 6);
            idx[c] = (k < mU) ? (int)U_s[k] : 0;
        }
#pragma unroll
        for (int c = 0; c < 8; ++c) flc[c] = used_s[idx[c]];
#pragma unroll
        for (int c = 0; c < 8; ++c) vv[c] = Lr[idx[c]];
#pragma unroll
        for (int c = 0; c < 8; ++c) {
            const int k = kbase + lane + (c << 6);
            if (k < mU && flc[c] == 0 &&
                (vv[c] > bv || (vv[c] == bv && idx[c] < bi))) {
                bv = vv[c]; bi = idx[c];
            }
        }
    }
    // 2-phase DPP argmax (val desc, idx asc) — r6 mechanism
    unsigned b = __float_as_uint(bv);
    unsigned key = (b & 0x80000000u) ? ~b : (b | 0x80000000u);
    const unsigned wk = wave_max_u32_dpp(key);
    const unsigned maxk = (unsigned)__builtin_amdgcn_readlane((int)wk, 63);
    unsigned cand = (key == maxk) ? (unsigned)(NS - bi) : 0u;
    const unsigned wc = wave_max_u32_dpp(cand);
    const unsigned mc = (unsigned)__builtin_amdgcn_readlane((int)wc, 63);
    return NS - (int)mc;
}

// ---------------- Kernel D: sequential greedy (single wave) ----------------
// Round-6 structure (651us) + two on-chain-only cuts (no memory pipelining —
// r11/r12/r13 proved hipcc defeats every multi-row value-prefetch scheme):
//  1. U8 register cache of the first 512 U_s indices (refreshed per rebuild):
//     removes the ~120cy idx-LDS read from every fallback chain.
//  2. TIGHT mode: once a full group of 8 rows all fall back, ballots are dead
//     (flags monotone; popular columns never free again) -> skip T-prefetch,
//     flag-prefetch and the 4-ballot preamble (~250cy) for remaining rows.
//     Exact: the fallback argmax IS the general path; ballot is a shortcut.
__global__ __launch_bounds__(64) void kD(const float* __restrict__ L,
                                         const unsigned short* __restrict__ top,
                                         int* __restrict__ assign) {
    __shared__ int used_s[NS];
    __shared__ int assign_s[NS];
    __shared__ unsigned short U_s[NS];
    const int lane = threadIdx.x;
    for (int k = lane; k < NS; k += 64) used_s[k] = 0;
    __syncthreads();

    const uint2* __restrict__ T = (const uint2*)top;   // T[row*64 + lane]

    uint2 buf[16];           // rows g..g+15
#pragma unroll
    for (int k = 0; k < 16; ++k) buf[k] = T[k * 64 + lane];

    int f0 = 0, f1 = 0, f2 = 0, f3 = 0;   // row-0 flags: nothing used yet
    int jprev = -1;
    int mU = NS;
    int U8[8];
    bool tight = false;

    for (int g = 0; g < NS; g += 8) {
        // ---- rebuild compact unused list every 64 rows ----
        if ((g & 63) == 0) {
            int fl[24];
#pragma unroll
            for (int k = 0; k < 24; ++k) fl[k] = used_s[lane + (k << 6)];
            int cnt = 0;
#pragma unroll
            for (int k = 0; k < 24; ++k) cnt += (fl[k] == 0);
            int incl = cnt;
#pragma unroll
            for (int o = 1; o < 64; o <<= 1) {
                const int v = __shfl_up(incl, o);
                if (lane >= o) incl += v;
            }
            int pos = incl - cnt;   // exclusive prefix
#pragma unroll
            for (int k = 0; k < 24; ++k) {
                if (fl[k] == 0) { U_s[pos] = (unsigned short)(lane + (k << 6)); ++pos; }
            }
            mU = __builtin_amdgcn_readlane(incl, 63);
            // refresh U8 register cache (single wave: LDS in-order, no barrier)
#pragma unroll
            for (int c = 0; c < 8; ++c) U8[c] = (int)U_s[lane + (c << 6)];
        }

        if (!tight) {
            // issue T loads for rows g+16..g+23 (consumed 2 groups from now)
            uint2 nb[8];
#pragma unroll
            for (int k = 0; k < 8; ++k) {
                int r = g + 16 + k;
                r = (r < NS) ? r : (NS - 1);
                nb[k] = T[r * 64 + lane];
            }

            int fbcnt = 0;
#pragma unroll
            for (int q = 0; q < 8; ++q) {
                const int i = g + q;

                // prefetch used-flags for row i+1 (candidates in buf[q+1])
                const uint2 pn = buf[q + 1];
                const int n0 = (int)(pn.x & 0xFFFFu), n1 = (int)(pn.x >> 16);
                const int n2 = (int)(pn.y & 0xFFFFu), n3 = (int)(pn.y >> 16);
                const int g0 = used_s[n0 < NS ? n0 : 0];
                const int g1 = used_s[n1 < NS ? n1 : 0];
                const int g2 = used_s[n2 < NS ? n2 : 0];
                const int g3 = used_s[n3 < NS ? n3 : 0];

                const uint2 pc = buf[q];
                const int c0 = (int)(pc.x & 0xFFFFu), c1 = (int)(pc.x >> 16);
                const int c2 = (int)(pc.y & 0xFFFFu), c3 = (int)(pc.y >> 16);
                const bool a0 = (c0 < NS) && (f0 == 0) && (c0 != jprev);
                const bool a1 = (c1 < NS) && (f1 == 0) && (c1 != jprev);
                const bool a2 = (c2 < NS) && (f2 == 0) && (c2 != jprev);
                const bool a3 = (c3 < NS) && (f3 == 0) && (c3 != jprev);
                const unsigned long long b0 = __ballot(a0);
                const unsigned long long b1 = __ballot(a1);
                const unsigned long long b2 = __ballot(a2);
                const unsigned long long b3 = __ballot(a3);

                int j;
                if (b0)      j = __builtin_amdgcn_readlane(c0, __ffsll(b0) - 1);
                else if (b1) j = __builtin_amdgcn_readlane(c1, __ffsll(b1) - 1);
                else if (b2) j = __builtin_amdgcn_readlane(c2, __ffsll(b2) - 1);
                else if (b3) j = __builtin_amdgcn_readlane(c3, __ffsll(b3) - 1);
                else {
                    ++fbcnt;
                    j = fb_argmax(L, i, mU, U8, used_s, U_s, lane);
                }
                if (lane == 0) { used_s[j] = 1; assign_s[i] = j; }
                jprev = j;
                f0 = g0; f1 = g1; f2 = g2; f3 = g3;
            }

            // rotate: waits only for loads issued ~8 rows ago (fully landed)
#pragma unroll
            for (int k = 0; k < 8; ++k) buf[k] = buf[k + 8];
#pragma unroll
            for (int k = 0; k < 8; ++k) buf[k + 8] = nb[k];

            tight = (fbcnt == 8);   // full-group fallback -> ballots are dead
        } else {
            // ---- TIGHT mode: fallback-only, no ballot preamble/prefetch ----
#pragma unroll 1
            for (int q = 0; q < 8; ++q) {
                const int i = g + q;
                const int j = fb_argmax(L, i, mU, U8, used_s, U_s, lane);
                if (lane == 0) { used_s[j] = 1; assign_s[i] = j; }
            }
        }
    }

    for (int k = lane; k < NS; k += 64) assign[k] = assign_s[k];
}

// ---------------- Kernel E: emit [1536][2][64] output ----------------
__global__ __launch_bounds__(128) void kE(const float* __restrict__ sat,
                                          const float* __restrict__ uav,
                                          const int* __restrict__ assign,
                                          float* __restrict__ out) {
    const int i = blockIdx.x;
    const int t = threadIdx.x;
    if (t < 64) out[(size_t)i * 128 + t] = sat[(size_t)i * DD + t];
    else        out[(size_t)i * 128 + t] = uav[(size_t)assign[i] * DD + (t - 64)];
}

extern "C" void kernel_launch(void* const* d_in, const int* in_sizes, int n_in,
                              void* d_out, int out_size, void* d_ws, size_t ws_size,
                              hipStream_t stream) {
    const float* sat = (const float*)d_in[0];
    const float* uav = (const float*)d_in[1];
    const float* W1  = (const float*)d_in[2];
    const float* b1  = (const float*)d_in[3];
    const float* W2  = (const float*)d_in[4];
    const float* b2  = (const float*)d_in[5];
    const float* W3  = (const float*)d_in[6];
    // d_in[7] = b3: sigmoid(x+b3) monotone in x — argmax unchanged.

    float* ws = (float*)d_ws;
    float* A   = ws + OFF_A;
    float* C2  = ws + OFF_C2;
    float* L   = ws + OFF_L;
    int* assign = (int*)(ws + OFF_AS);
    unsigned short* top = (unsigned short*)(ws + OFF_A);  // aliases A/C2 (dead after kB)

    hipLaunchKernelGGL(kA, dim3(NS), dim3(64), 0, stream, sat, uav, W1, b1, A, C2);
    hipLaunchKernelGGL(kB, dim3(NS / 4, NS / 256), dim3(256), 0, stream,
                       A, C2, W2, b2, W3, L);
    hipLaunchKernelGGL(kC, dim3(NS), dim3(256), 0, stream, L, top);
    hipLaunchKernelGGL(kD, dim3(1), dim3(64), 0, stream, L, top, assign);
    hipLaunchKernelGGL(kE, dim3(NS), dim3(128), 0, stream, sat, uav, assign,
                       (float*)d_out);
}